// Round 1
// baseline (1195.585 us; speedup 1.0000x reference)
//
#include <hip/hip_runtime.h>
#include <cstdint>
#include <cstddef>

#define N_ROWS 262144
#define D 256
#define K_CODES 640
#define BM 128
#define KT 32
#define PAD 132           // padded leading dim for [KT][BM] LDS tiles (16B-aligned rows, conflict-light)
#define TAU 0.25f         // flag threshold: >> 2x worst-case fp32 score error (~3e-3)

__constant__ int d_STARTS[6] = {0, 129, 257, 385, 513, 577};
__constant__ int d_ENDS[6]   = {128, 256, 384, 512, 576, 640};

__device__ __forceinline__ int partition_id(int a) {
    int p = 3;
    if (a == 5) p = 0;
    else if (a == 6) p = 1;
    else if (a == 7) p = 2;
    else if (a == 119) p = 4;
    else if (a == 120) p = 5;
    return p;
}

// ---- ws layout (bytes) ----
// 0      : double loss accumulator
// 8      : double wnorm2[640]
// 5128   : int counts[6]
// 5152   : int bases[6]
// 5176   : int cursors[6]
// 5200   : int flagcnt
// 8192   : int rowlist[N]
// 8192+4N: int flagrows[N]

__global__ void k_zero(int* ws_i) {
    int t = threadIdx.x;
    for (int i = t; i < 2048; i += 256) ws_i[i] = 0;   // zero first 8192 bytes
}

__global__ void k_wnorm(const float* __restrict__ w, double* __restrict__ wnorm2) {
    int k = blockIdx.x;
    int l = threadIdx.x;  // 64 threads
    const float* row = w + (size_t)k * D;
    double s = 0.0;
    for (int j = l; j < D; j += 64) {
        double v = (double)row[j];
        s += v * v;
    }
    #pragma unroll
    for (int m = 32; m > 0; m >>= 1) s += __shfl_xor(s, m, 64);
    if (l == 0) wnorm2[k] = s;
}

__global__ void k_count(const int* __restrict__ x, int* __restrict__ counts) {
    __shared__ int lc[6];
    int t = threadIdx.x;
    if (t < 6) lc[t] = 0;
    __syncthreads();
    int r = blockIdx.x * 256 + t;
    int p = partition_id(x[2 * r]);
    atomicAdd(&lc[p], 1);
    __syncthreads();
    if (t < 6) atomicAdd(&counts[t], lc[t]);
}

__global__ void k_scan(const int* __restrict__ counts, int* __restrict__ bases,
                       int* __restrict__ cursors) {
    if (threadIdx.x == 0) {
        int b = 0;
        for (int p = 0; p < 6; p++) {
            bases[p] = b;
            cursors[p] = b;
            b += counts[p];
        }
    }
}

__global__ void k_scatter(const int* __restrict__ x, int* __restrict__ cursors,
                          int* __restrict__ rowlist) {
    int t = threadIdx.x;
    int r = blockIdx.x * 256 + t;
    int p = partition_id(x[2 * r]);
    int lane = t & 63;
    for (int q = 0; q < 6; q++) {
        unsigned long long m = __ballot(p == q);
        if (p == q) {
            int leader = __builtin_ctzll(m);
            int prefix = __popcll(m & ((1ull << lane) - 1ull));
            int base = 0;
            if (lane == leader) base = atomicAdd(&cursors[q], __popcll(m));
            base = __shfl(base, leader, 64);
            rowlist[base + prefix] = r;
        }
    }
}

// Pass A: per-partition tiled fp32 GEMM (128 rows x 128 codes per block, 8x8 per thread)
// tracks best-2 scores per row; small-gap rows are flagged for exact fp64 fix-up.
__launch_bounds__(256, 3)
__global__ void k_passA(const float* __restrict__ e, const float* __restrict__ w,
                        const int* __restrict__ counts, const int* __restrict__ bases,
                        const int* __restrict__ rowlist, const double* __restrict__ wnorm2,
                        float* __restrict__ out, double* __restrict__ loss,
                        int* __restrict__ flagcnt, int* __restrict__ flagrows) {
    // map block -> (partition p, segment seg)
    int b = blockIdx.x;
    int p = -1, seg = 0;
    {
        int acc = 0;
        for (int q = 0; q < 6; q++) {
            int nb = (counts[q] + BM - 1) / BM;
            if (b < acc + nb) { p = q; seg = b - acc; break; }
            acc += nb;
        }
    }
    if (p < 0) return;

    int cstart = d_STARTS[p], cend = d_ENDS[p];
    int cnt = counts[p];
    int base = bases[p] + seg * BM;
    int nrows = min(BM, cnt - seg * BM);

    __shared__ int rl[BM];
    __shared__ __align__(16) float eT[KT * PAD];
    __shared__ __align__(16) float wT[KT * PAD];
    __shared__ int bestk[BM];
    __shared__ double lred[4];

    int tid = threadIdx.x;
    int tx = tid & 15;   // code group: codes cstart + 8*tx .. +7
    int ty = tid >> 4;   // row group : slots 8*ty .. +7

    if (tid < BM) rl[tid] = (tid < nrows) ? rowlist[base + tid] : -1;
    __syncthreads();

    float acc[8][8];
    #pragma unroll
    for (int i = 0; i < 8; i++)
        #pragma unroll
        for (int j = 0; j < 8; j++) acc[i][j] = 0.f;

    double lsum = 0.0;  // per-thread: sum of e^2 (staged elems) + later best scores

    for (int t0 = 0; t0 < D; t0 += KT) {
        if (t0) __syncthreads();
        // stage e-tile (transposed) and w-tile: 1024 float4 slots each, 4 per thread
        #pragma unroll
        for (int i = 0; i < 4; i++) {
            int s = tid + 256 * i;
            int row = s >> 3;       // 0..127
            int c = s & 7;          // which float4 of the 32 d-values
            int gr = rl[row];
            float4 ev = make_float4(0.f, 0.f, 0.f, 0.f);
            if (gr >= 0) ev = *(const float4*)(e + (size_t)gr * D + t0 + 4 * c);
            lsum += (double)((double)ev.x * ev.x + (double)ev.y * ev.y +
                             (double)ev.z * ev.z + (double)ev.w * ev.w);
            eT[(4 * c + 0) * PAD + row] = ev.x;
            eT[(4 * c + 1) * PAD + row] = ev.y;
            eT[(4 * c + 2) * PAD + row] = ev.z;
            eT[(4 * c + 3) * PAD + row] = ev.w;

            int k = cstart + row;
            int kk = (k < cend) ? k : (cend - 1);   // clamp: garbage masked later
            float4 wv = *(const float4*)(w + (size_t)kk * D + t0 + 4 * c);
            wT[(4 * c + 0) * PAD + row] = wv.x;
            wT[(4 * c + 1) * PAD + row] = wv.y;
            wT[(4 * c + 2) * PAD + row] = wv.z;
            wT[(4 * c + 3) * PAD + row] = wv.w;
        }
        __syncthreads();
        #pragma unroll
        for (int d = 0; d < KT; d++) {
            const float4* ep = (const float4*)&eT[d * PAD + 8 * ty];
            float4 ea = ep[0], eb = ep[1];
            const float4* wp = (const float4*)&wT[d * PAD + 8 * tx];
            float4 wa = wp[0], wb = wp[1];
            float ee[8] = {ea.x, ea.y, ea.z, ea.w, eb.x, eb.y, eb.z, eb.w};
            float ww[8] = {wa.x, wa.y, wa.z, wa.w, wb.x, wb.y, wb.z, wb.w};
            #pragma unroll
            for (int i = 0; i < 8; i++)
                #pragma unroll
                for (int j = 0; j < 8; j++)
                    acc[i][j] = fmaf(ee[i], ww[j], acc[i][j]);
        }
    }

    // scores + best-2 per row, reduce across the 16 tx lanes
    float wn[8];
    #pragma unroll
    for (int j = 0; j < 8; j++) {
        int k = cstart + 8 * tx + j;
        wn[j] = (k < cend) ? (float)wnorm2[k] : 0.f;
    }
    const float INFF = 3.4e38f;
    #pragma unroll
    for (int i = 0; i < 8; i++) {
        float b1 = INFF, b2 = INFF;
        int c1 = 1 << 30, c2 = 1 << 30;
        #pragma unroll
        for (int j = 0; j < 8; j++) {
            int k = cstart + 8 * tx + j;
            float s = (k < cend) ? (wn[j] - 2.0f * acc[i][j]) : INFF;
            if (s < b1) { b2 = b1; c2 = c1; b1 = s; c1 = k; }
            else if (s < b2) { b2 = s; c2 = k; }
        }
        #pragma unroll
        for (int m = 1; m < 16; m <<= 1) {
            float ob1 = __shfl_xor(b1, m, 64), ob2 = __shfl_xor(b2, m, 64);
            int oc1 = __shfl_xor(c1, m, 64), oc2 = __shfl_xor(c2, m, 64);
            bool oWins = (ob1 < b1) || (ob1 == b1 && oc1 < c1);
            if (oWins) {
                float nb2; int nc2;
                if (b1 < ob2 || (b1 == ob2 && c1 < oc2)) { nb2 = b1; nc2 = c1; }
                else { nb2 = ob2; nc2 = oc2; }
                b1 = ob1; c1 = oc1; b2 = nb2; c2 = nc2;
            } else {
                if (ob1 < b2 || (ob1 == b2 && oc1 < c2)) { b2 = ob1; c2 = oc1; }
            }
        }
        if (tx == 0) {
            int slot = 8 * ty + i;
            if (slot < nrows) {
                if (b2 - b1 < TAU) {
                    int pos = atomicAdd(flagcnt, 1);
                    flagrows[pos] = rl[slot];
                    bestk[slot] = -1;           // handled exactly in pass B
                } else {
                    bestk[slot] = c1;
                    lsum += (double)b1;         // ||q||^2 - 2 e.q contribution
                }
            } else {
                bestk[slot] = -1;
            }
        }
    }
    __syncthreads();

    // write out rows (one element per thread per row), skipping flagged rows
    for (int rsl = 0; rsl < nrows; rsl++) {
        int k = bestk[rsl];
        if (k >= 0) {
            int gr = rl[rsl];
            out[(size_t)gr * D + tid] = w[(size_t)k * D + tid];
        }
    }

    // block loss reduction -> one fp64 atomic
    #pragma unroll
    for (int m = 32; m > 0; m >>= 1) lsum += __shfl_xor(lsum, m, 64);
    int wid = tid >> 6, lane = tid & 63;
    if (lane == 0) lred[wid] = lsum;
    __syncthreads();
    if (tid == 0) atomicAdd(loss, lred[0] + lred[1] + lred[2] + lred[3]);
}

// Pass B: exact fp64 re-evaluation for flagged (near-tie) rows. One block per row.
__global__ void k_passB(const float* __restrict__ e, const float* __restrict__ w,
                        const int* __restrict__ x, const double* __restrict__ wnorm2,
                        const int* __restrict__ flagcnt, const int* __restrict__ flagrows,
                        float* __restrict__ out, double* __restrict__ loss) {
    __shared__ float eL[D];
    __shared__ double sc[256];
    __shared__ int sk[256];
    int t = threadIdx.x;
    int nf = *flagcnt;
    for (int f = blockIdx.x; f < nf; f += gridDim.x) {
        int gr = flagrows[f];
        eL[t] = e[(size_t)gr * D + t];
        __syncthreads();
        int p = partition_id(x[2 * gr]);
        int cs = d_STARTS[p], ce = d_ENDS[p];
        int k = cs + t;
        double score; int kk;
        if (k < ce) {
            const float* wr = w + (size_t)k * D;
            double dot = 0.0;
            for (int d = 0; d < D; d++) dot += (double)eL[d] * (double)wr[d];
            score = wnorm2[k] - 2.0 * dot;
            kk = k;
        } else {
            score = 1e300; kk = 1 << 30;
        }
        sc[t] = score; sk[t] = kk;
        __syncthreads();
        for (int s = 128; s > 0; s >>= 1) {
            if (t < s) {
                double o = sc[t + s]; int ok = sk[t + s];
                if (o < sc[t] || (o == sc[t] && ok < sk[t])) { sc[t] = o; sk[t] = ok; }
            }
            __syncthreads();
        }
        int bk = sk[0];
        double bs = sc[0];
        out[(size_t)gr * D + t] = w[(size_t)bk * D + t];
        if (t == 0) atomicAdd(loss, bs);   // ||e||^2 part was added in pass A staging
        __syncthreads();
    }
}

__global__ void k_final(const double* __restrict__ loss, float* __restrict__ out) {
    if (threadIdx.x == 0) {
        double mean = *loss / ((double)N_ROWS * (double)D);
        size_t nd = (size_t)N_ROWS * D;
        out[nd + 0] = (float)mean;          // codebook_loss
        out[nd + 1] = (float)mean;          // gnn_loss (numerically identical)
        out[nd + 2] = (float)(1.25 * mean); // vq_loss = codebook + 0.25*gnn
    }
}

extern "C" void kernel_launch(void* const* d_in, const int* in_sizes, int n_in,
                              void* d_out, int out_size, void* d_ws, size_t ws_size,
                              hipStream_t stream) {
    const int* x = (const int*)d_in[0];
    const float* e = (const float*)d_in[1];
    const float* w = (const float*)d_in[2];
    float* out = (float*)d_out;
    char* ws = (char*)d_ws;

    double* loss    = (double*)(ws + 0);
    double* wnorm2  = (double*)(ws + 8);
    int* counts     = (int*)(ws + 5128);
    int* bases      = (int*)(ws + 5152);
    int* cursors    = (int*)(ws + 5176);
    int* flagcnt    = (int*)(ws + 5200);
    int* rowlist    = (int*)(ws + 8192);
    int* flagrows   = (int*)(ws + 8192 + 4 * (size_t)N_ROWS);

    k_zero<<<1, 256, 0, stream>>>((int*)ws);
    k_wnorm<<<K_CODES, 64, 0, stream>>>(w, wnorm2);
    k_count<<<N_ROWS / 256, 256, 0, stream>>>(x, counts);
    k_scan<<<1, 64, 0, stream>>>(counts, bases, cursors);
    k_scatter<<<N_ROWS / 256, 256, 0, stream>>>(x, cursors, rowlist);
    k_passA<<<N_ROWS / BM + 5, 256, 0, stream>>>(e, w, counts, bases, rowlist, wnorm2,
                                                 out, loss, flagcnt, flagrows);
    k_passB<<<128, 256, 0, stream>>>(e, w, x, wnorm2, flagcnt, flagrows, out, loss);
    k_final<<<1, 64, 0, stream>>>(loss, out);
}

// Round 2
// 709.344 us; speedup vs baseline: 1.6855x; 1.6855x over previous
//
#include <hip/hip_runtime.h>
#include <cstdint>
#include <cstddef>

#define N_ROWS 262144
#define D 256
#define K_CODES 640
#define BM 128
#define BK 32
#define PA 40             // LDS row pitch in bf16 (32 + 8 pad): 80B rows -> 2-way-only conflicts
#define TAU 0.05f         // flag threshold: ~7x worst-case split-bf16 score error (~7e-3)

typedef __attribute__((ext_vector_type(8))) short bf16x8;
typedef __attribute__((ext_vector_type(4))) float f32x4;

__constant__ int d_STARTS[6] = {0, 129, 257, 385, 513, 577};
__constant__ int d_ENDS[6]   = {128, 256, 384, 512, 576, 640};

__device__ __forceinline__ int partition_id(int a) {
    int p = 3;
    if (a == 5) p = 0;
    else if (a == 6) p = 1;
    else if (a == 7) p = 2;
    else if (a == 119) p = 4;
    else if (a == 120) p = 5;
    return p;
}

__device__ __forceinline__ unsigned short f32_to_bf16_rne(float x) {
    unsigned int u = __float_as_uint(x);
    u += 0x7FFFu + ((u >> 16) & 1u);
    return (unsigned short)(u >> 16);
}

// ---- ws layout (bytes) ----
// 0      : double loss accumulator
// 8      : double wnorm2[640]
// 5128   : int counts[6]
// 5152   : int bases[6]
// 5176   : int cursors[6]
// 5200   : int flagcnt
// 8192   : int rowlist[N]
// 8192+4N: int flagrows[N]

__global__ void k_zero(int* ws_i) {
    int t = threadIdx.x;
    for (int i = t; i < 2048; i += 256) ws_i[i] = 0;
}

__global__ void k_wnorm(const float* __restrict__ w, double* __restrict__ wnorm2) {
    int k = blockIdx.x;
    int l = threadIdx.x;  // 64 threads
    const float* row = w + (size_t)k * D;
    double s = 0.0;
    for (int j = l; j < D; j += 64) {
        double v = (double)row[j];
        s += v * v;
    }
    #pragma unroll
    for (int m = 32; m > 0; m >>= 1) s += __shfl_xor(s, m, 64);
    if (l == 0) wnorm2[k] = s;
}

__global__ void k_count(const int* __restrict__ x, int* __restrict__ counts) {
    __shared__ int lc[6];
    int t = threadIdx.x;
    if (t < 6) lc[t] = 0;
    __syncthreads();
    int r = blockIdx.x * 256 + t;
    int p = partition_id(x[2 * r]);
    atomicAdd(&lc[p], 1);
    __syncthreads();
    if (t < 6) atomicAdd(&counts[t], lc[t]);
}

__global__ void k_scan(const int* __restrict__ counts, int* __restrict__ bases,
                       int* __restrict__ cursors) {
    if (threadIdx.x == 0) {
        int b = 0;
        for (int p = 0; p < 6; p++) {
            bases[p] = b;
            cursors[p] = b;
            b += counts[p];
        }
    }
}

__global__ void k_scatter(const int* __restrict__ x, int* __restrict__ cursors,
                          int* __restrict__ rowlist) {
    int t = threadIdx.x;
    int r = blockIdx.x * 256 + t;
    int p = partition_id(x[2 * r]);
    int lane = t & 63;
    for (int q = 0; q < 6; q++) {
        unsigned long long m = __ballot(p == q);
        if (p == q) {
            int leader = __builtin_ctzll(m);
            int prefix = __popcll(m & ((1ull << lane) - 1ull));
            int base = 0;
            if (lane == leader) base = atomicAdd(&cursors[q], __popcll(m));
            base = __shfl(base, leader, 64);
            rowlist[base + prefix] = r;
        }
    }
}

// Pass A: split-bf16 MFMA GEMM. Block = 128 rows x 128 codes (one partition tile).
// dot(e,w) ~= hi_e*hi_w + lo_e*hi_w + hi_e*lo_w  (3 MFMAs into one fp32 acc).
// Per-row best-2 tracked; gap < TAU rows flagged for exact fp64 pass B.
__launch_bounds__(256, 3)
__global__ void k_passA(const float* __restrict__ e, const float* __restrict__ w,
                        const int* __restrict__ counts, const int* __restrict__ bases,
                        const int* __restrict__ rowlist, const double* __restrict__ wnorm2,
                        float* __restrict__ out, double* __restrict__ loss,
                        int* __restrict__ flagcnt, int* __restrict__ flagrows) {
    int b = blockIdx.x;
    int p = -1, seg = 0;
    {
        int acc0 = 0;
        for (int q = 0; q < 6; q++) {
            int nb = (counts[q] + BM - 1) / BM;
            if (b < acc0 + nb) { p = q; seg = b - acc0; break; }
            acc0 += nb;
        }
    }
    if (p < 0) return;

    int cstart = d_STARTS[p], cend = d_ENDS[p];
    int cnt = counts[p];
    int base = bases[p] + seg * BM;
    int nrows = min(BM, cnt - seg * BM);

    __shared__ int rl[BM];
    __shared__ float wnf[BM];
    __shared__ __align__(16) unsigned short Ahi[BM * PA];
    __shared__ __align__(16) unsigned short Alo[BM * PA];
    __shared__ __align__(16) unsigned short Bhi[BM * PA];
    __shared__ __align__(16) unsigned short Blo[BM * PA];
    __shared__ int bestk[BM];
    __shared__ double lred[4];

    int tid = threadIdx.x;
    int lane = tid & 63;
    int wid = tid >> 6;

    if (tid < BM) {
        rl[tid] = (tid < nrows) ? rowlist[base + tid] : -1;
        int k = cstart + tid;
        wnf[tid] = (k < cend) ? (float)wnorm2[k] : __int_as_float(0x7f800000);
    }
    __syncthreads();

    f32x4 acc[2][8];
    #pragma unroll
    for (int t = 0; t < 2; t++)
        #pragma unroll
        for (int ct = 0; ct < 8; ct++)
            acc[t][ct] = (f32x4){0.f, 0.f, 0.f, 0.f};

    double lsum = 0.0;

    int srow = tid >> 1;         // staging row 0..127
    int shalf = tid & 1;         // which half of the 8 float4s
    int gr = rl[srow];
    const float* ebase = e + (size_t)(gr < 0 ? 0 : gr) * D;
    int kk = cstart + srow;
    if (kk >= cend) kk = cend - 1;
    const float* wbase = w + (size_t)kk * D;

    int m16 = lane & 15;
    int k8 = (lane >> 4) * 8;

    for (int t0 = 0; t0 < D; t0 += BK) {
        if (t0) __syncthreads();
        // stage e (hi/lo) and w (hi/lo): 2 threads per row, 4 float4 each
        #pragma unroll
        for (int i = 0; i < 4; i++) {
            int c = shalf * 4 + i;            // float4 index within the 32-wide tile
            float4 ev = make_float4(0.f, 0.f, 0.f, 0.f);
            if (gr >= 0) ev = *(const float4*)(ebase + t0 + 4 * c);
            lsum += (double)ev.x * ev.x + (double)ev.y * ev.y +
                    (double)ev.z * ev.z + (double)ev.w * ev.w;
            unsigned short h0 = f32_to_bf16_rne(ev.x), h1 = f32_to_bf16_rne(ev.y);
            unsigned short h2 = f32_to_bf16_rne(ev.z), h3 = f32_to_bf16_rne(ev.w);
            float l0 = ev.x - __uint_as_float((unsigned)h0 << 16);
            float l1 = ev.y - __uint_as_float((unsigned)h1 << 16);
            float l2 = ev.z - __uint_as_float((unsigned)h2 << 16);
            float l3 = ev.w - __uint_as_float((unsigned)h3 << 16);
            uint2 hp = make_uint2((unsigned)h0 | ((unsigned)h1 << 16),
                                  (unsigned)h2 | ((unsigned)h3 << 16));
            uint2 lp = make_uint2((unsigned)f32_to_bf16_rne(l0) | ((unsigned)f32_to_bf16_rne(l1) << 16),
                                  (unsigned)f32_to_bf16_rne(l2) | ((unsigned)f32_to_bf16_rne(l3) << 16));
            *(uint2*)&Ahi[srow * PA + 4 * c] = hp;
            *(uint2*)&Alo[srow * PA + 4 * c] = lp;

            float4 wv = *(const float4*)(wbase + t0 + 4 * c);
            unsigned short g0 = f32_to_bf16_rne(wv.x), g1 = f32_to_bf16_rne(wv.y);
            unsigned short g2 = f32_to_bf16_rne(wv.z), g3 = f32_to_bf16_rne(wv.w);
            float m0 = wv.x - __uint_as_float((unsigned)g0 << 16);
            float m1 = wv.y - __uint_as_float((unsigned)g1 << 16);
            float m2 = wv.z - __uint_as_float((unsigned)g2 << 16);
            float m3 = wv.w - __uint_as_float((unsigned)g3 << 16);
            uint2 gp = make_uint2((unsigned)g0 | ((unsigned)g1 << 16),
                                  (unsigned)g2 | ((unsigned)g3 << 16));
            uint2 mp = make_uint2((unsigned)f32_to_bf16_rne(m0) | ((unsigned)f32_to_bf16_rne(m1) << 16),
                                  (unsigned)f32_to_bf16_rne(m2) | ((unsigned)f32_to_bf16_rne(m3) << 16));
            *(uint2*)&Bhi[srow * PA + 4 * c] = gp;
            *(uint2*)&Blo[srow * PA + 4 * c] = mp;
        }
        __syncthreads();

        // MFMA: wave `wid` owns rows 32*wid..32*wid+31, all 128 cols
        bf16x8 a_h[2], a_l[2];
        #pragma unroll
        for (int t = 0; t < 2; t++) {
            int r = 32 * wid + 16 * t + m16;
            a_h[t] = *(const bf16x8*)&Ahi[r * PA + k8];
            a_l[t] = *(const bf16x8*)&Alo[r * PA + k8];
        }
        #pragma unroll
        for (int ct = 0; ct < 8; ct++) {
            int cr = 16 * ct + m16;
            bf16x8 b_h = *(const bf16x8*)&Bhi[cr * PA + k8];
            bf16x8 b_l = *(const bf16x8*)&Blo[cr * PA + k8];
            #pragma unroll
            for (int t = 0; t < 2; t++) {
                acc[t][ct] = __builtin_amdgcn_mfma_f32_16x16x32_bf16(a_h[t], b_h, acc[t][ct], 0, 0, 0);
                acc[t][ct] = __builtin_amdgcn_mfma_f32_16x16x32_bf16(a_l[t], b_h, acc[t][ct], 0, 0, 0);
                acc[t][ct] = __builtin_amdgcn_mfma_f32_16x16x32_bf16(a_h[t], b_l, acc[t][ct], 0, 0, 0);
            }
        }
    }

    // epilogue: per-lane wnorm for its 8 cols
    float wl[8];
    #pragma unroll
    for (int ct = 0; ct < 8; ct++) wl[ct] = wnf[16 * ct + m16];

    const float INFF = __int_as_float(0x7f800000);
    #pragma unroll
    for (int t = 0; t < 2; t++) {
        #pragma unroll
        for (int reg = 0; reg < 4; reg++) {
            int slot = 32 * wid + 16 * t + (lane >> 4) * 4 + reg;
            float b1 = INFF, b2 = INFF;
            int c1 = 1 << 30, c2 = 1 << 30;
            #pragma unroll
            for (int ct = 0; ct < 8; ct++) {
                float s = wl[ct] - 2.0f * acc[t][ct][reg];
                int k = cstart + 16 * ct + m16;
                if (s < b1) { b2 = b1; c2 = c1; b1 = s; c1 = k; }
                else if (s < b2) { b2 = s; c2 = k; }
            }
            #pragma unroll
            for (int m = 1; m < 16; m <<= 1) {
                float ob1 = __shfl_xor(b1, m, 64), ob2 = __shfl_xor(b2, m, 64);
                int oc1 = __shfl_xor(c1, m, 64), oc2 = __shfl_xor(c2, m, 64);
                bool oWins = (ob1 < b1) || (ob1 == b1 && oc1 < c1);
                if (oWins) {
                    float nb2; int nc2;
                    if (b1 < ob2 || (b1 == ob2 && c1 < oc2)) { nb2 = b1; nc2 = c1; }
                    else { nb2 = ob2; nc2 = oc2; }
                    b1 = ob1; c1 = oc1; b2 = nb2; c2 = nc2;
                } else {
                    if (ob1 < b2 || (ob1 == b2 && oc1 < c2)) { b2 = ob1; c2 = oc1; }
                }
            }
            if (m16 == 0) {
                if (slot < nrows) {
                    if (b2 - b1 < TAU) {
                        int pos = atomicAdd(flagcnt, 1);
                        flagrows[pos] = rl[slot];
                        bestk[slot] = -1;
                    } else {
                        bestk[slot] = c1;
                        lsum += (double)b1;
                    }
                } else {
                    bestk[slot] = -1;
                }
            }
        }
    }
    __syncthreads();

    // write out rows, skipping flagged
    for (int rsl = 0; rsl < nrows; rsl++) {
        int k = bestk[rsl];
        if (k >= 0) {
            int g = rl[rsl];
            out[(size_t)g * D + tid] = w[(size_t)k * D + tid];
        }
    }

    #pragma unroll
    for (int m = 32; m > 0; m >>= 1) lsum += __shfl_xor(lsum, m, 64);
    if ((tid & 63) == 0) lred[wid] = lsum;
    __syncthreads();
    if (tid == 0) atomicAdd(loss, lred[0] + lred[1] + lred[2] + lred[3]);
}

// Pass B: exact fp64 re-evaluation of flagged rows. 512 blocks, grid-stride.
__global__ void k_passB(const float* __restrict__ e, const float* __restrict__ w,
                        const int* __restrict__ x, const double* __restrict__ wnorm2,
                        const int* __restrict__ flagcnt, const int* __restrict__ flagrows,
                        float* __restrict__ out, double* __restrict__ loss) {
    __shared__ float eL[D];
    __shared__ double sc[128];
    __shared__ int sk[128];
    int t = threadIdx.x;
    int nf = *flagcnt;
    for (int f = blockIdx.x; f < nf; f += gridDim.x) {
        int gr = flagrows[f];
        eL[t] = e[(size_t)gr * D + t];
        __syncthreads();
        int p = partition_id(x[2 * gr]);
        int cs = d_STARTS[p], ce = d_ENDS[p];
        if (t < 128) {
            int k = cs + t;
            if (k < ce) {
                const float* wr = w + (size_t)k * D;
                double d0 = 0.0, d1 = 0.0, d2 = 0.0, d3 = 0.0;
                #pragma unroll 4
                for (int d = 0; d < D; d += 4) {
                    d0 += (double)eL[d + 0] * (double)wr[d + 0];
                    d1 += (double)eL[d + 1] * (double)wr[d + 1];
                    d2 += (double)eL[d + 2] * (double)wr[d + 2];
                    d3 += (double)eL[d + 3] * (double)wr[d + 3];
                }
                sc[t] = wnorm2[k] - 2.0 * ((d0 + d1) + (d2 + d3));
                sk[t] = k;
            } else {
                sc[t] = 1e300;
                sk[t] = 1 << 30;
            }
        }
        __syncthreads();
        for (int s = 64; s > 0; s >>= 1) {
            if (t < s) {
                double o = sc[t + s]; int ok = sk[t + s];
                if (o < sc[t] || (o == sc[t] && ok < sk[t])) { sc[t] = o; sk[t] = ok; }
            }
            __syncthreads();
        }
        int bk = sk[0];
        out[(size_t)gr * D + t] = w[(size_t)bk * D + t];
        if (t == 0) atomicAdd(loss, sc[0]);
        __syncthreads();
    }
}

__global__ void k_final(const double* __restrict__ loss, float* __restrict__ out) {
    if (threadIdx.x == 0) {
        double mean = *loss / ((double)N_ROWS * (double)D);
        size_t nd = (size_t)N_ROWS * D;
        out[nd + 0] = (float)mean;
        out[nd + 1] = (float)mean;
        out[nd + 2] = (float)(1.25 * mean);
    }
}

extern "C" void kernel_launch(void* const* d_in, const int* in_sizes, int n_in,
                              void* d_out, int out_size, void* d_ws, size_t ws_size,
                              hipStream_t stream) {
    const int* x = (const int*)d_in[0];
    const float* e = (const float*)d_in[1];
    const float* w = (const float*)d_in[2];
    float* out = (float*)d_out;
    char* ws = (char*)d_ws;

    double* loss    = (double*)(ws + 0);
    double* wnorm2  = (double*)(ws + 8);
    int* counts     = (int*)(ws + 5128);
    int* bases      = (int*)(ws + 5152);
    int* cursors    = (int*)(ws + 5176);
    int* flagcnt    = (int*)(ws + 5200);
    int* rowlist    = (int*)(ws + 8192);
    int* flagrows   = (int*)(ws + 8192 + 4 * (size_t)N_ROWS);

    k_zero<<<1, 256, 0, stream>>>((int*)ws);
    k_wnorm<<<K_CODES, 64, 0, stream>>>(w, wnorm2);
    k_count<<<N_ROWS / 256, 256, 0, stream>>>(x, counts);
    k_scan<<<1, 64, 0, stream>>>(counts, bases, cursors);
    k_scatter<<<N_ROWS / 256, 256, 0, stream>>>(x, cursors, rowlist);
    k_passA<<<N_ROWS / BM + 5, 256, 0, stream>>>(e, w, counts, bases, rowlist, wnorm2,
                                                 out, loss, flagcnt, flagrows);
    k_passB<<<512, 256, 0, stream>>>(e, w, x, wnorm2, flagcnt, flagrows, out, loss);
    k_final<<<1, 64, 0, stream>>>(loss, out);
}